// Round 7
// baseline (161.734 us; speedup 1.0000x reference)
//
#include <hip/hip_runtime.h>
#include <cstddef>
#include <cstdint>

// ---------------------------------------------------------------------------
// x [N=32, C=256, H=64, W=64] fp32. Branches: sq 3x3 pad(1,1) ch 64..127,
// ver 3x1 pad(1,0) ch 128..191, hor 1x3 pad(0,1) ch 192..255. CondConv K=4.
// Training-mode BN per branch, concat(s0,sq,ve,ho), channel_shuffle(g=8):
//   c_out = (c_pre % 32)*8 + c_pre/32
// Conv: per-sample GEMM on matrix cores, bf16 in / fp32 accum.
// Round 7: (1) conv writes bf16 scratch (50 MB, LLC-friendly) instead of
// fp32 out (-100 MB HBM); bn reads bf16, writes fp32 out. BN stats still
// from fp32 accums. (2) s0 copy moved into prepass. (3) XCD-aware block
// swizzle on conv_all so same-n blocks share wbf/xt in one XCD's L2.
// ---------------------------------------------------------------------------

typedef __attribute__((ext_vector_type(8))) short frag8;    // 8 bf16 = 4 VGPR
typedef __attribute__((ext_vector_type(16))) float accf16;  // 32x32 accum

#define HW 4096
#define CNT_INV (1.0f / 131072.0f)
#define CSTR 1056                 // chunk stride bytes: 66 slots * 16
#define RSTR 8448                 // row stride bytes: 8 chunks * CSTR
#define XT_BR (32ull * 66 * 8448) // bytes per branch of transposed x

// workspace offsets (4-byte units)
#define WS_POOLED 0            // 6144
#define WS_SS     6528         // 384 (3 * 128)
#define WS_PST    6912         // 3 * 65536
#define WS_WBF_SQ  203520      // 589824 u32 (bf16 pairs)
#define WS_WBF_VER 793344      // 196608
#define WS_WBF_HOR 989952      // 196608
#define WS_XT      1186560     // 3 * XT_BR bytes
#define WS_CVOUT   14568448    // 32*192*4096 u16 = 6291456 u32

__device__ __forceinline__ int shuf_ch(int c) { return ((c & 31) << 3) | (c >> 5); }

__device__ __forceinline__ unsigned bf16pair(float a, float b) {
    unsigned ua = __builtin_bit_cast(unsigned, a);
    unsigned ub = __builtin_bit_cast(unsigned, b);
    ua = (ua + 0x7fffu + ((ua >> 16) & 1u)) >> 16;   // round-to-nearest-even
    ub = (ub + 0x7fffu + ((ub >> 16) & 1u)) >> 16;
    return ua | (ub << 16);
}

__device__ __forceinline__ unsigned short bf16r(float a) {
    unsigned ua = __builtin_bit_cast(unsigned, a);
    return (unsigned short)((ua + 0x7fffu + ((ua >> 16) & 1u)) >> 16);
}

__device__ __forceinline__ float bf16lo(unsigned u) {
    return __builtin_bit_cast(float, u << 16);
}
__device__ __forceinline__ float bf16hi(unsigned u) {
    return __builtin_bit_cast(float, u & 0xffff0000u);
}

__device__ __forceinline__ void gload_lds16(const void* g, void* l) {
    __builtin_amdgcn_global_load_lds(
        (const __attribute__((address_space(1))) void*)g,
        (__attribute__((address_space(3))) void*)l, 16, 0, 0);
}

// ---- 1. prepass: pool + bf16 transpose into conv tile layout; + s0 copy ----
__global__ void __launch_bounds__(256) prepass_kernel(
    const float* __restrict__ x, unsigned char* __restrict__ xt,
    float* __restrict__ pooled, float* __restrict__ out) {
    const int bid = blockIdx.x;           // 768 transpose + 256 s0 blocks
    const int tid = threadIdx.x;

    if (bid >= 768) {                     // s0 identity -> shuffled out
        const int sid = bid - 768;
        const int c8 = sid & 7, n = sid >> 3;
#pragma unroll
        for (int j = 0; j < 8; ++j) {
            const int c = c8 * 8 + j;
            const float4* s = (const float4*)(x + (size_t)(n * 256 + c) * HW);
            float4* d = (float4*)(out + (size_t)(n * 256 + shuf_ch(c)) * HW);
#pragma unroll
            for (int it = 0; it < 4; ++it) d[tid + it * 256] = s[tid + it * 256];
        }
        return;
    }

    const int c8 = bid & 7;
    const int n = (bid >> 3) & 31;
    const int b = bid >> 8;
    const int w = tid & 63, q = tid >> 6;
    const float* xb = x + (size_t)(n * 256 + 64 * (b + 1) + c8 * 8) * HW;
    unsigned char* xtb = xt + (size_t)b * XT_BR + (size_t)n * 66 * RSTR + c8 * CSTR;

    float ps[8] = {0.f, 0.f, 0.f, 0.f, 0.f, 0.f, 0.f, 0.f};
    for (int h = q; h < 64; h += 4) {
        float v[8];
#pragma unroll
        for (int j = 0; j < 8; ++j) v[j] = xb[(size_t)j * HW + h * 64 + w];
        unsigned pk[4];
#pragma unroll
        for (int j = 0; j < 4; ++j) pk[j] = bf16pair(v[2 * j], v[2 * j + 1]);
        *(uint4*)(xtb + (size_t)(h + 1) * RSTR + (w + 1) * 16) = *(uint4*)pk;
#pragma unroll
        for (int j = 0; j < 8; ++j) ps[j] += v[j];
    }
    // zero halo: rows 0,65 (all 66 slots); rows 1..64 slots 0,65
    for (int idx = tid; idx < 260; idx += 256) {
        int p, slot;
        if (idx < 66)       { p = 0;         slot = idx; }
        else if (idx < 132) { p = 65;        slot = idx - 66; }
        else if (idx < 196) { p = idx - 131; slot = 0; }
        else                { p = idx - 195; slot = 65; }
        *(uint4*)(xtb + (size_t)p * RSTR + slot * 16) = uint4{0, 0, 0, 0};
    }
    // pool reduce
    __shared__ float red[4][8];
#pragma unroll
    for (int j = 0; j < 8; ++j)
#pragma unroll
        for (int off = 32; off; off >>= 1) ps[j] += __shfl_down(ps[j], off, 64);
    if ((tid & 63) == 0)
#pragma unroll
        for (int j = 0; j < 8; ++j) red[q][j] = ps[j];
    __syncthreads();
    if (tid < 8)
        pooled[(b * 32 + n) * 64 + c8 * 8 + tid] =
            (red[0][tid] + red[1][tid] + red[2][tid] + red[3][tid]) * (1.f / 4096.f);
}

// ---- 2. expert-mix weights -> bf16, layout [n][tap][frag][o][4u32] ---------
template <int TAPS>
__device__ __forceinline__ void aggbf_body(const float* __restrict__ w,
                                           const float* __restrict__ pooled_b,
                                           const float* __restrict__ aw,
                                           const float* __restrict__ ab,
                                           unsigned* __restrict__ wbf, int bid) {
    const int tid = threadIdx.x;
    int idx = bid * 256 + tid;                    // (n*TAPS+t)*2048 + o*32 + ip
    int ip = idx & 31;
    int o  = (idx >> 5) & 63;
    int t  = (idx >> 11) % TAPS;
    int n  = (idx >> 11) / TAPS;

    __shared__ float satt[4];
    if (tid < 64) {
        float p = pooled_b[n * 64 + tid];
#pragma unroll
        for (int k = 0; k < 4; ++k) {
            float v = p * aw[k * 64 + tid];
#pragma unroll
            for (int off = 32; off; off >>= 1) v += __shfl_down(v, off, 64);
            if (tid == 0) satt[k] = 1.f / (1.f + expf(-(v + ab[k])));
        }
    }
    __syncthreads();
    const float a0 = satt[0], a1 = satt[1], a2 = satt[2], a3 = satt[3];

    constexpr int PS = 64 * 64 * TAPS;
    int base = (o * 64 + ip * 2) * TAPS + t;      // w[k][o][i][t]
    float v0 = a0*w[base] + a1*w[PS+base] + a2*w[2*PS+base] + a3*w[3*PS+base];
    int base1 = base + TAPS;
    float v1 = a0*w[base1] + a1*w[PS+base1] + a2*w[2*PS+base1] + a3*w[3*PS+base1];
    // coalesced layout: u32 idx = (((n*T+t)*8 + f)*64 + o)*4 + jj
    int f = ip >> 2, jj = ip & 3;
    wbf[(((n * TAPS + t) * 8 + f) * 64 + o) * 4 + jj] = bf16pair(v0, v1);
}

__global__ void __launch_bounds__(256) aggbf_all_kernel(
    const float* __restrict__ pooled,
    const float* __restrict__ aw0, const float* __restrict__ ab0,
    const float* __restrict__ aw1, const float* __restrict__ ab1,
    const float* __restrict__ aw2, const float* __restrict__ ab2,
    const float* __restrict__ sq_w, const float* __restrict__ ver_w,
    const float* __restrict__ hor_w,
    unsigned* __restrict__ wsq, unsigned* __restrict__ wver,
    unsigned* __restrict__ whor) {
    int bid = blockIdx.x;
    if (bid < 2304)
        aggbf_body<9>(sq_w, pooled, aw0, ab0, wsq, bid);
    else if (bid < 3072)
        aggbf_body<3>(ver_w, pooled + 2048, aw1, ab1, wver, bid - 2304);
    else
        aggbf_body<3>(hor_w, pooled + 4096, aw2, ab2, whor, bid - 3072);
}

// ---- 3. fused conv (3 branches), bf16 scratch output -----------------------
#define LOADA(dst, tt) \
    _Pragma("unroll") for (int kk = 0; kk < 4; ++kk) { \
        dst[kk]     = wp[(tt) * 512 + kk * 128]; \
        dst[4 + kk] = wp[(tt) * 512 + kk * 128 + 32]; \
    }

#define TAPSTEP(tt, CUR) { \
    const int r_ = (tt) / KW, dw_ = (tt) % KW - PW; \
    const unsigned char* bp_ = xs + (rh * 2 + r_) * RSTR + hi * CSTR + \
                               (wcol + dw_ + 1) * 16; \
    _Pragma("unroll") for (int kk = 0; kk < 4; ++kk) { \
        frag8 b0 = *(const frag8*)(bp_ + kk * 2 * CSTR); \
        frag8 b1 = *(const frag8*)(bp_ + kk * 2 * CSTR + RSTR); \
        a00 = __builtin_amdgcn_mfma_f32_32x32x16_bf16(CUR[kk],     b0, a00, 0, 0, 0); \
        a10 = __builtin_amdgcn_mfma_f32_32x32x16_bf16(CUR[4 + kk], b0, a10, 0, 0, 0); \
        a01 = __builtin_amdgcn_mfma_f32_32x32x16_bf16(CUR[kk],     b1, a01, 0, 0, 0); \
        a11 = __builtin_amdgcn_mfma_f32_32x32x16_bf16(CUR[4 + kk], b1, a11, 0, 0, 0); \
    } }

template <int KH, int KW, int PH, int PW>
__device__ __forceinline__ void conv_body(
    const unsigned char* __restrict__ xt, const unsigned* __restrict__ wbf,
    unsigned short* __restrict__ cvout, float* __restrict__ pst, int cbase,
    int bid, unsigned char* xs, float (*red1)[2][2][16],
    float (*red2)[2][2][16]) {
    constexpr int TAPS = KH * KW;
    constexpr int HB = 4;
    constexpr int ROWS = HB + KH - 1;
    constexpr int TOT = ROWS * RSTR;
    constexpr int NCH = (TOT + 1023) >> 10;   // 50 (KH=3) / 33 (KH=1)
    const int hb = bid & 15, n = bid >> 4;
    const int h0 = hb * HB;
    const int tid = threadIdx.x;
    const int lane = tid & 63;
    const int wv = tid >> 6;
    const int rh = wv >> 1, wn = wv & 1;  // wave = (row-half, w-half)
    const int l31 = lane & 31, hi = lane >> 5;
    const int wcol = wn * 32 + l31;

    // DMA-stage ROWS rows (contiguous span, pre-transposed, halos pre-zeroed)
    {
        const unsigned char* src = xt +
            (size_t)(n * 66 + h0 + (KH == 1 ? 1 : 0)) * RSTR + lane * 16;
#pragma unroll
        for (int c = wv; c < NCH; c += 4)
            gload_lds16(src + (c << 10), xs + (c << 10));
    }

    // A base: frag f=kk*2+hi, row l31 (+32): wp[t*512 + f*64 + row]
    const frag8* wp = (const frag8*)wbf + (size_t)n * TAPS * 512 + hi * 64 + l31;

    frag8 aA[8], aB[8];
    LOADA(aA, 0);                          // in flight during staging wait
    __syncthreads();

    accf16 a00 = {}, a01 = {}, a10 = {}, a11 = {};   // a{o-half}{row}
#pragma unroll
    for (int t = 0; t < TAPS; t += 2) {
        if (t + 1 < TAPS) LOADA(aB, t + 1);
        TAPSTEP(t, aA);
        if (t + 2 < TAPS) LOADA(aA, t + 2);
        if (t + 1 < TAPS) TAPSTEP(t + 1, aB);
    }

    // C write: bf16 scratch [n][c_pre-64][h][w] (shuffle applied in bn pass)
    {
        unsigned short* cb = cvout + (size_t)(n * 192 + (cbase - 64)) * HW +
                             (h0 + rh * 2) * 64 + wcol;
#pragma unroll
        for (int rg = 0; rg < 16; ++rg) {
            const int o = (rg & 3) + 8 * (rg >> 2) + 4 * hi;
            unsigned short* p0 = cb + (size_t)o * HW;
            p0[0]  = bf16r(a00[rg]);
            p0[64] = bf16r(a01[rg]);
            unsigned short* p1 = cb + (size_t)(o + 32) * HW;
            p1[0]  = bf16r(a10[rg]);
            p1[64] = bf16r(a11[rg]);
        }
    }

    // BN partial sums (from unrounded fp32 accums)
#pragma unroll
    for (int rg = 0; rg < 16; ++rg) {
        float u1 = a00[rg] + a01[rg];
        float u2 = a00[rg] * a00[rg] + a01[rg] * a01[rg];
        float w1 = a10[rg] + a11[rg];
        float w2 = a10[rg] * a10[rg] + a11[rg] * a11[rg];
#pragma unroll
        for (int off = 16; off; off >>= 1) {
            u1 += __shfl_down(u1, off, 32);
            u2 += __shfl_down(u2, off, 32);
            w1 += __shfl_down(w1, off, 32);
            w2 += __shfl_down(w2, off, 32);
        }
        if (l31 == 0) {
            red1[wv][0][hi][rg] = u1; red2[wv][0][hi][rg] = u2;
            red1[wv][1][hi][rg] = w1; red2[wv][1][hi][rg] = w2;
        }
    }
    __syncthreads();
    if (tid < 64) {
        const int rg = tid & 15, hi2 = (tid >> 4) & 1, wm2 = tid >> 5;
        float s1 = 0.f, s2 = 0.f;
#pragma unroll
        for (int v = 0; v < 4; ++v) {
            s1 += red1[v][wm2][hi2][rg];
            s2 += red2[v][wm2][hi2][rg];
        }
        const int o = wm2 * 32 + (rg & 3) + 8 * (rg >> 2) + 4 * hi2;
        const int slot = n * 16 + hb;
        pst[o * 1024 + slot] = s1;
        pst[o * 1024 + 512 + slot] = s2;
    }
}

__global__ void __launch_bounds__(256, 3) conv_all_kernel(
    const unsigned char* __restrict__ xt,
    const unsigned* __restrict__ wsq, const unsigned* __restrict__ wver,
    const unsigned* __restrict__ whor,
    unsigned short* __restrict__ cvout, float* __restrict__ pst) {
    __shared__ __align__(16) unsigned char xs[6 * RSTR + 512];
    __shared__ float red1[4][2][2][16], red2[4][2][2][16];
    // XCD-aware swizzle (1536 % 8 == 0 -> bijective): same-n blocks
    // land on one XCD so wbf + xt halos L2-hit.
    int bid = (blockIdx.x & 7) * 192 + (blockIdx.x >> 3);
    if (bid < 512)
        conv_body<3, 3, 1, 1>(xt, wsq, cvout, pst, 64, bid, xs, red1, red2);
    else if (bid < 1024)
        conv_body<3, 1, 1, 0>(xt + XT_BR, wver, cvout, pst + 65536, 128,
                              bid - 512, xs, red1, red2);
    else
        conv_body<1, 3, 0, 1>(xt + 2 * XT_BR, whor, cvout, pst + 131072, 192,
                              bid - 1024, xs, red1, red2);
}

// ---- 4. reduce BN partials -> scale/shift, all branches --------------------
__global__ void __launch_bounds__(256) bnstats_all_kernel(
    const float* __restrict__ pst,
    const float* __restrict__ g0, const float* __restrict__ b0,
    const float* __restrict__ g1, const float* __restrict__ b1,
    const float* __restrict__ g2, const float* __restrict__ b2,
    float* __restrict__ ss) {
    int br = blockIdx.x >> 6, o = blockIdx.x & 63, t = threadIdx.x;
    const float* gamma = (br == 0) ? g0 : (br == 1) ? g1 : g2;
    const float* beta  = (br == 0) ? b0 : (br == 1) ? b1 : b2;
    const float* p = pst + br * 65536 + o * 1024;
    float s1 = 0.f, s2 = 0.f;
    for (int i = t; i < 512; i += 256) {
        s1 += p[i];
        s2 += p[512 + i];
    }
#pragma unroll
    for (int off = 32; off; off >>= 1) {
        s1 += __shfl_down(s1, off, 64);
        s2 += __shfl_down(s2, off, 64);
    }
    __shared__ float r1[4], r2[4];
    if ((t & 63) == 0) { r1[t >> 6] = s1; r2[t >> 6] = s2; }
    __syncthreads();
    if (t == 0) {
        float S1 = r1[0] + r1[1] + r1[2] + r1[3];
        float S2 = r2[0] + r2[1] + r2[2] + r2[3];
        float mean = S1 * CNT_INV;
        float var = S2 * CNT_INV - mean * mean;
        float scale = rsqrtf(var + 1e-5f) * gamma[o];
        ss[br * 128 + o * 2 + 0] = scale;
        ss[br * 128 + o * 2 + 1] = beta[o] - mean * scale;
    }
}

// ---- 5. BN apply: read bf16 scratch, write fp32 out (shuffled) -------------
__global__ void __launch_bounds__(256) bn_all_kernel(
    const unsigned short* __restrict__ cvout, float* __restrict__ out,
    const float* __restrict__ ss) {
    int g = blockIdx.x;                  // ((sub*64+o)*32+n)*2+half, 12288
    int half = g & 1;
    int n = (g >> 1) & 31;
    int o = (g >> 6) & 63;
    int sub = g >> 12;
    float scale = ss[sub * 128 + o * 2], shift = ss[sub * 128 + o * 2 + 1];
    const uint4* src = (const uint4*)(cvout +
        (size_t)(n * 192 + sub * 64 + o) * HW + half * 2048) + threadIdx.x;
    float* dst = out + (size_t)(n * 256 + shuf_ch(64 * (sub + 1) + o)) * HW +
                 half * 2048 + threadIdx.x * 8;
    uint4 r = *src;
    float4 f0, f1;
    f0.x = fmaf(bf16lo(r.x), scale, shift);
    f0.y = fmaf(bf16hi(r.x), scale, shift);
    f0.z = fmaf(bf16lo(r.y), scale, shift);
    f0.w = fmaf(bf16hi(r.y), scale, shift);
    f1.x = fmaf(bf16lo(r.z), scale, shift);
    f1.y = fmaf(bf16hi(r.z), scale, shift);
    f1.z = fmaf(bf16lo(r.w), scale, shift);
    f1.w = fmaf(bf16hi(r.w), scale, shift);
    *(float4*)dst = f0;
    *(float4*)(dst + 4) = f1;
}

extern "C" void kernel_launch(void* const* d_in, const int* in_sizes, int n_in,
                              void* d_out, int out_size, void* d_ws, size_t ws_size,
                              hipStream_t stream) {
    const float* x        = (const float*)d_in[0];
    const float* sq_att_w = (const float*)d_in[1];
    const float* sq_att_b = (const float*)d_in[2];
    const float* sq_w     = (const float*)d_in[3];
    const float* sq_g     = (const float*)d_in[4];
    const float* sq_b     = (const float*)d_in[5];
    const float* ver_att_w= (const float*)d_in[6];
    const float* ver_att_b= (const float*)d_in[7];
    const float* ver_w    = (const float*)d_in[8];
    const float* ver_g    = (const float*)d_in[9];
    const float* ver_b    = (const float*)d_in[10];
    const float* hor_att_w= (const float*)d_in[11];
    const float* hor_att_b= (const float*)d_in[12];
    const float* hor_w    = (const float*)d_in[13];
    const float* hor_g    = (const float*)d_in[14];
    const float* hor_b    = (const float*)d_in[15];
    float* out = (float*)d_out;
    float* ws = (float*)d_ws;

    float* pooled = ws + WS_POOLED;
    float* ss     = ws + WS_SS;
    float* pst    = ws + WS_PST;
    unsigned* wbf_sq  = (unsigned*)(ws + WS_WBF_SQ);
    unsigned* wbf_ver = (unsigned*)(ws + WS_WBF_VER);
    unsigned* wbf_hor = (unsigned*)(ws + WS_WBF_HOR);
    unsigned char* xt = (unsigned char*)(ws + WS_XT);
    unsigned short* cvout = (unsigned short*)(ws + WS_CVOUT);

    prepass_kernel<<<1024, 256, 0, stream>>>(x, xt, pooled, out);
    aggbf_all_kernel<<<3840, 256, 0, stream>>>(pooled,
                                               sq_att_w, sq_att_b,
                                               ver_att_w, ver_att_b,
                                               hor_att_w, hor_att_b,
                                               sq_w, ver_w, hor_w,
                                               wbf_sq, wbf_ver, wbf_hor);
    conv_all_kernel<<<1536, 256, 0, stream>>>(xt, wbf_sq, wbf_ver, wbf_hor,
                                              cvout, pst);
    bnstats_all_kernel<<<192, 256, 0, stream>>>(pst, sq_g, sq_b, ver_g, ver_b,
                                                hor_g, hor_b, ss);
    bn_all_kernel<<<12288, 256, 0, stream>>>(cvout, out, ss);
}

// Round 8
// 144.021 us; speedup vs baseline: 1.1230x; 1.1230x over previous
//
#include <hip/hip_runtime.h>
#include <cstddef>
#include <cstdint>

// ---------------------------------------------------------------------------
// x [N=32, C=256, H=64, W=64] fp32. Branches: sq 3x3 pad(1,1) ch 64..127,
// ver 3x1 pad(1,0) ch 128..191, hor 1x3 pad(0,1) ch 192..255. CondConv K=4.
// Training-mode BN per branch, concat(s0,sq,ve,ho), channel_shuffle(g=8):
//   c_out = (c_pre % 32)*8 + c_pre/32
// Conv: per-sample GEMM on matrix cores, bf16 in / fp32 accum.
// Round 8: prepass was 86us @ 1.8TB/s, latency-bound (4 blocks/CU, serial
// h-loop). Now 3072 blocks (h-quartered, fully unrolled -> 32 loads in
// flight), pool via 4 partial slots summed in aggbf. s0 copy moved into
// conv_all's tail (fills conv's idle BW).
// ---------------------------------------------------------------------------

typedef __attribute__((ext_vector_type(8))) short frag8;    // 8 bf16 = 4 VGPR
typedef __attribute__((ext_vector_type(16))) float accf16;  // 32x32 accum

#define HW 4096
#define CNT_INV (1.0f / 131072.0f)
#define CSTR 1056                 // chunk stride bytes: 66 slots * 16
#define RSTR 8448                 // row stride bytes: 8 chunks * CSTR
#define XT_BR (32ull * 66 * 8448) // bytes per branch of transposed x

// workspace offsets (4-byte units)
#define WS_POOLED 0            // 4 * 6144 partial sums
#define WS_SS     24576        // 384 (3 * 128)
#define WS_PST    24960        // 3 * 65536
#define WS_WBF_SQ  221568      // 589824 u32 (bf16 pairs)
#define WS_WBF_VER 811392      // 196608
#define WS_WBF_HOR 1008000     // 196608
#define WS_XT      1204608     // 3 * XT_BR bytes
#define WS_CVOUT   14586240    // 32*192*4096 u16

__device__ __forceinline__ int shuf_ch(int c) { return ((c & 31) << 3) | (c >> 5); }

__device__ __forceinline__ unsigned bf16pair(float a, float b) {
    unsigned ua = __builtin_bit_cast(unsigned, a);
    unsigned ub = __builtin_bit_cast(unsigned, b);
    ua = (ua + 0x7fffu + ((ua >> 16) & 1u)) >> 16;   // round-to-nearest-even
    ub = (ub + 0x7fffu + ((ub >> 16) & 1u)) >> 16;
    return ua | (ub << 16);
}

__device__ __forceinline__ unsigned short bf16r(float a) {
    unsigned ua = __builtin_bit_cast(unsigned, a);
    return (unsigned short)((ua + 0x7fffu + ((ua >> 16) & 1u)) >> 16);
}

__device__ __forceinline__ float bf16lo(unsigned u) {
    return __builtin_bit_cast(float, u << 16);
}
__device__ __forceinline__ float bf16hi(unsigned u) {
    return __builtin_bit_cast(float, u & 0xffff0000u);
}

__device__ __forceinline__ void gload_lds16(const void* g, void* l) {
    __builtin_amdgcn_global_load_lds(
        (const __attribute__((address_space(1))) void*)g,
        (__attribute__((address_space(3))) void*)l, 16, 0, 0);
}

// ---- 1. prepass: bf16 transpose into conv tile layout + pool partials ------
__global__ void __launch_bounds__(256) prepass_kernel(
    const float* __restrict__ x, unsigned char* __restrict__ xt,
    float* __restrict__ pooled4) {
    const int bid = blockIdx.x;           // ((b*32+n)*8+c8)*4+hq, 3072 blocks
    const int hq = bid & 3;
    const int c8 = (bid >> 2) & 7;
    const int n = (bid >> 5) & 31;
    const int b = bid >> 10;
    const int tid = threadIdx.x;
    const int w = tid & 63, q = tid >> 6;
    const float* xb = x + (size_t)(n * 256 + 64 * (b + 1) + c8 * 8) * HW;
    unsigned char* xtb = xt + (size_t)b * XT_BR + (size_t)n * 66 * RSTR + c8 * CSTR;

    float ps[8] = {0.f, 0.f, 0.f, 0.f, 0.f, 0.f, 0.f, 0.f};
#pragma unroll
    for (int it = 0; it < 4; ++it) {
        const int h = hq * 16 + it * 4 + q;
        float v[8];
#pragma unroll
        for (int j = 0; j < 8; ++j) v[j] = xb[(size_t)j * HW + h * 64 + w];
        unsigned pk[4];
#pragma unroll
        for (int j = 0; j < 4; ++j) pk[j] = bf16pair(v[2 * j], v[2 * j + 1]);
        *(uint4*)(xtb + (size_t)(h + 1) * RSTR + (w + 1) * 16) = *(uint4*)pk;
#pragma unroll
        for (int j = 0; j < 8; ++j) ps[j] += v[j];
    }
    // halo zero (hq==0 block only): rows 0,65 all slots; rows 1..64 slots 0,65
    if (hq == 0) {
        for (int idx = tid; idx < 260; idx += 256) {
            int p, slot;
            if (idx < 66)       { p = 0;         slot = idx; }
            else if (idx < 132) { p = 65;        slot = idx - 66; }
            else if (idx < 196) { p = idx - 131; slot = 0; }
            else                { p = idx - 195; slot = 65; }
            *(uint4*)(xtb + (size_t)p * RSTR + slot * 16) = uint4{0, 0, 0, 0};
        }
    }
    // pool partial reduce -> slot [hq][(b*32+n)*64 + c8*8 + j]
    __shared__ float red[4][8];
#pragma unroll
    for (int j = 0; j < 8; ++j)
#pragma unroll
        for (int off = 32; off; off >>= 1) ps[j] += __shfl_down(ps[j], off, 64);
    if ((tid & 63) == 0)
#pragma unroll
        for (int j = 0; j < 8; ++j) red[q][j] = ps[j];
    __syncthreads();
    if (tid < 8)
        pooled4[hq * 6144 + (b * 32 + n) * 64 + c8 * 8 + tid] =
            red[0][tid] + red[1][tid] + red[2][tid] + red[3][tid];
}

// ---- 2. expert-mix weights -> bf16, layout [n][tap][frag][o][4u32] ---------
template <int TAPS>
__device__ __forceinline__ void aggbf_body(const float* __restrict__ w,
                                           const float* __restrict__ pooled_b,
                                           const float* __restrict__ aw,
                                           const float* __restrict__ ab,
                                           unsigned* __restrict__ wbf, int bid) {
    const int tid = threadIdx.x;
    int idx = bid * 256 + tid;                    // (n*TAPS+t)*2048 + o*32 + ip
    int ip = idx & 31;
    int o  = (idx >> 5) & 63;
    int t  = (idx >> 11) % TAPS;
    int n  = (idx >> 11) / TAPS;

    __shared__ float satt[4];
    if (tid < 64) {
        const int base = n * 64 + tid;
        float p = (pooled_b[base] + pooled_b[base + 6144] +
                   pooled_b[base + 12288] + pooled_b[base + 18432]) *
                  (1.f / 4096.f);
#pragma unroll
        for (int k = 0; k < 4; ++k) {
            float v = p * aw[k * 64 + tid];
#pragma unroll
            for (int off = 32; off; off >>= 1) v += __shfl_down(v, off, 64);
            if (tid == 0) satt[k] = 1.f / (1.f + expf(-(v + ab[k])));
        }
    }
    __syncthreads();
    const float a0 = satt[0], a1 = satt[1], a2 = satt[2], a3 = satt[3];

    constexpr int PS = 64 * 64 * TAPS;
    int base = (o * 64 + ip * 2) * TAPS + t;      // w[k][o][i][t]
    float v0 = a0*w[base] + a1*w[PS+base] + a2*w[2*PS+base] + a3*w[3*PS+base];
    int base1 = base + TAPS;
    float v1 = a0*w[base1] + a1*w[PS+base1] + a2*w[2*PS+base1] + a3*w[3*PS+base1];
    // coalesced layout: u32 idx = (((n*T+t)*8 + f)*64 + o)*4 + jj
    int f = ip >> 2, jj = ip & 3;
    wbf[(((n * TAPS + t) * 8 + f) * 64 + o) * 4 + jj] = bf16pair(v0, v1);
}

__global__ void __launch_bounds__(256) aggbf_all_kernel(
    const float* __restrict__ pooled,
    const float* __restrict__ aw0, const float* __restrict__ ab0,
    const float* __restrict__ aw1, const float* __restrict__ ab1,
    const float* __restrict__ aw2, const float* __restrict__ ab2,
    const float* __restrict__ sq_w, const float* __restrict__ ver_w,
    const float* __restrict__ hor_w,
    unsigned* __restrict__ wsq, unsigned* __restrict__ wver,
    unsigned* __restrict__ whor) {
    int bid = blockIdx.x;
    if (bid < 2304)
        aggbf_body<9>(sq_w, pooled, aw0, ab0, wsq, bid);
    else if (bid < 3072)
        aggbf_body<3>(ver_w, pooled + 2048, aw1, ab1, wver, bid - 2304);
    else
        aggbf_body<3>(hor_w, pooled + 4096, aw2, ab2, whor, bid - 3072);
}

// ---- 3. fused conv (3 branches) + s0 copy, bf16 scratch output -------------
#define LOADA(dst, tt) \
    _Pragma("unroll") for (int kk = 0; kk < 4; ++kk) { \
        dst[kk]     = wp[(tt) * 512 + kk * 128]; \
        dst[4 + kk] = wp[(tt) * 512 + kk * 128 + 32]; \
    }

#define TAPSTEP(tt, CUR) { \
    const int r_ = (tt) / KW, dw_ = (tt) % KW - PW; \
    const unsigned char* bp_ = xs + (rh * 2 + r_) * RSTR + hi * CSTR + \
                               (wcol + dw_ + 1) * 16; \
    _Pragma("unroll") for (int kk = 0; kk < 4; ++kk) { \
        frag8 b0 = *(const frag8*)(bp_ + kk * 2 * CSTR); \
        frag8 b1 = *(const frag8*)(bp_ + kk * 2 * CSTR + RSTR); \
        a00 = __builtin_amdgcn_mfma_f32_32x32x16_bf16(CUR[kk],     b0, a00, 0, 0, 0); \
        a10 = __builtin_amdgcn_mfma_f32_32x32x16_bf16(CUR[4 + kk], b0, a10, 0, 0, 0); \
        a01 = __builtin_amdgcn_mfma_f32_32x32x16_bf16(CUR[kk],     b1, a01, 0, 0, 0); \
        a11 = __builtin_amdgcn_mfma_f32_32x32x16_bf16(CUR[4 + kk], b1, a11, 0, 0, 0); \
    } }

template <int KH, int KW, int PH, int PW>
__device__ __forceinline__ void conv_body(
    const unsigned char* __restrict__ xt, const unsigned* __restrict__ wbf,
    unsigned short* __restrict__ cvout, float* __restrict__ pst, int cbase,
    int bid, unsigned char* xs, float (*red1)[2][2][16],
    float (*red2)[2][2][16]) {
    constexpr int TAPS = KH * KW;
    constexpr int HB = 4;
    constexpr int ROWS = HB + KH - 1;
    constexpr int TOT = ROWS * RSTR;
    constexpr int NCH = (TOT + 1023) >> 10;   // 50 (KH=3) / 33 (KH=1)
    const int hb = bid & 15, n = bid >> 4;
    const int h0 = hb * HB;
    const int tid = threadIdx.x;
    const int lane = tid & 63;
    const int wv = tid >> 6;
    const int rh = wv >> 1, wn = wv & 1;  // wave = (row-half, w-half)
    const int l31 = lane & 31, hi = lane >> 5;
    const int wcol = wn * 32 + l31;

    // DMA-stage ROWS rows (contiguous span, pre-transposed, halos pre-zeroed)
    {
        const unsigned char* src = xt +
            (size_t)(n * 66 + h0 + (KH == 1 ? 1 : 0)) * RSTR + lane * 16;
#pragma unroll
        for (int c = wv; c < NCH; c += 4)
            gload_lds16(src + (c << 10), xs + (c << 10));
    }

    // A base: frag f=kk*2+hi, row l31 (+32): wp[t*512 + f*64 + row]
    const frag8* wp = (const frag8*)wbf + (size_t)n * TAPS * 512 + hi * 64 + l31;

    frag8 aA[8], aB[8];
    LOADA(aA, 0);                          // in flight during staging wait
    __syncthreads();

    accf16 a00 = {}, a01 = {}, a10 = {}, a11 = {};   // a{o-half}{row}
#pragma unroll
    for (int t = 0; t < TAPS; t += 2) {
        if (t + 1 < TAPS) LOADA(aB, t + 1);
        TAPSTEP(t, aA);
        if (t + 2 < TAPS) LOADA(aA, t + 2);
        if (t + 1 < TAPS) TAPSTEP(t + 1, aB);
    }

    // C write: bf16 scratch [n][c_pre-64][h][w] (shuffle applied in bn pass)
    {
        unsigned short* cb = cvout + (size_t)(n * 192 + (cbase - 64)) * HW +
                             (h0 + rh * 2) * 64 + wcol;
#pragma unroll
        for (int rg = 0; rg < 16; ++rg) {
            const int o = (rg & 3) + 8 * (rg >> 2) + 4 * hi;
            unsigned short* p0 = cb + (size_t)o * HW;
            p0[0]  = bf16r(a00[rg]);
            p0[64] = bf16r(a01[rg]);
            unsigned short* p1 = cb + (size_t)(o + 32) * HW;
            p1[0]  = bf16r(a10[rg]);
            p1[64] = bf16r(a11[rg]);
        }
    }

    // BN partial sums (from unrounded fp32 accums)
#pragma unroll
    for (int rg = 0; rg < 16; ++rg) {
        float u1 = a00[rg] + a01[rg];
        float u2 = a00[rg] * a00[rg] + a01[rg] * a01[rg];
        float w1 = a10[rg] + a11[rg];
        float w2 = a10[rg] * a10[rg] + a11[rg] * a11[rg];
#pragma unroll
        for (int off = 16; off; off >>= 1) {
            u1 += __shfl_down(u1, off, 32);
            u2 += __shfl_down(u2, off, 32);
            w1 += __shfl_down(w1, off, 32);
            w2 += __shfl_down(w2, off, 32);
        }
        if (l31 == 0) {
            red1[wv][0][hi][rg] = u1; red2[wv][0][hi][rg] = u2;
            red1[wv][1][hi][rg] = w1; red2[wv][1][hi][rg] = w2;
        }
    }
    __syncthreads();
    if (tid < 64) {
        const int rg = tid & 15, hi2 = (tid >> 4) & 1, wm2 = tid >> 5;
        float s1 = 0.f, s2 = 0.f;
#pragma unroll
        for (int v = 0; v < 4; ++v) {
            s1 += red1[v][wm2][hi2][rg];
            s2 += red2[v][wm2][hi2][rg];
        }
        const int o = wm2 * 32 + (rg & 3) + 8 * (rg >> 2) + 4 * hi2;
        const int slot = n * 16 + hb;
        pst[o * 1024 + slot] = s1;
        pst[o * 1024 + 512 + slot] = s2;
    }
}

__device__ __forceinline__ void s0_body(const float* __restrict__ x,
                                        float* __restrict__ out, int sid) {
    const int c8 = sid & 7, n = sid >> 3, tid = threadIdx.x;
#pragma unroll
    for (int j = 0; j < 8; ++j) {
        const int c = c8 * 8 + j;
        const float4* s = (const float4*)(x + (size_t)(n * 256 + c) * HW);
        float4* d = (float4*)(out + (size_t)(n * 256 + shuf_ch(c)) * HW);
#pragma unroll
        for (int it = 0; it < 4; ++it) d[tid + it * 256] = s[tid + it * 256];
    }
}

__global__ void __launch_bounds__(256, 3) conv_all_kernel(
    const float* __restrict__ x, const unsigned char* __restrict__ xt,
    const unsigned* __restrict__ wsq, const unsigned* __restrict__ wver,
    const unsigned* __restrict__ whor,
    unsigned short* __restrict__ cvout, float* __restrict__ pst,
    float* __restrict__ out) {
    __shared__ __align__(16) unsigned char xs[6 * RSTR + 512];
    __shared__ float red1[4][2][2][16], red2[4][2][2][16];
    int raw = blockIdx.x;                 // 1536 conv + 256 s0
    if (raw >= 1536) { s0_body(x, out, raw - 1536); return; }
    // XCD-aware swizzle (1536 % 8 == 0 -> bijective): same-n blocks
    // land on one XCD so wbf + xt halos L2-hit.
    int bid = (raw & 7) * 192 + (raw >> 3);
    if (bid < 512)
        conv_body<3, 3, 1, 1>(xt, wsq, cvout, pst, 64, bid, xs, red1, red2);
    else if (bid < 1024)
        conv_body<3, 1, 1, 0>(xt + XT_BR, wver, cvout, pst + 65536, 128,
                              bid - 512, xs, red1, red2);
    else
        conv_body<1, 3, 0, 1>(xt + 2 * XT_BR, whor, cvout, pst + 131072, 192,
                              bid - 1024, xs, red1, red2);
}

// ---- 4. reduce BN partials -> scale/shift, all branches --------------------
__global__ void __launch_bounds__(256) bnstats_all_kernel(
    const float* __restrict__ pst,
    const float* __restrict__ g0, const float* __restrict__ b0,
    const float* __restrict__ g1, const float* __restrict__ b1,
    const float* __restrict__ g2, const float* __restrict__ b2,
    float* __restrict__ ss) {
    int br = blockIdx.x >> 6, o = blockIdx.x & 63, t = threadIdx.x;
    const float* gamma = (br == 0) ? g0 : (br == 1) ? g1 : g2;
    const float* beta  = (br == 0) ? b0 : (br == 1) ? b1 : b2;
    const float* p = pst + br * 65536 + o * 1024;
    float s1 = 0.f, s2 = 0.f;
    for (int i = t; i < 512; i += 256) {
        s1 += p[i];
        s2 += p[512 + i];
    }
#pragma unroll
    for (int off = 32; off; off >>= 1) {
        s1 += __shfl_down(s1, off, 64);
        s2 += __shfl_down(s2, off, 64);
    }
    __shared__ float r1[4], r2[4];
    if ((t & 63) == 0) { r1[t >> 6] = s1; r2[t >> 6] = s2; }
    __syncthreads();
    if (t == 0) {
        float S1 = r1[0] + r1[1] + r1[2] + r1[3];
        float S2 = r2[0] + r2[1] + r2[2] + r2[3];
        float mean = S1 * CNT_INV;
        float var = S2 * CNT_INV - mean * mean;
        float scale = rsqrtf(var + 1e-5f) * gamma[o];
        ss[br * 128 + o * 2 + 0] = scale;
        ss[br * 128 + o * 2 + 1] = beta[o] - mean * scale;
    }
}

// ---- 5. BN apply: read bf16 scratch, write fp32 out (shuffled) -------------
__global__ void __launch_bounds__(256) bn_all_kernel(
    const unsigned short* __restrict__ cvout, float* __restrict__ out,
    const float* __restrict__ ss) {
    int g = blockIdx.x;                  // ((sub*64+o)*32+n)*2+half, 12288
    int half = g & 1;
    int n = (g >> 1) & 31;
    int o = (g >> 6) & 63;
    int sub = g >> 12;
    float scale = ss[sub * 128 + o * 2], shift = ss[sub * 128 + o * 2 + 1];
    const uint4* src = (const uint4*)(cvout +
        (size_t)(n * 192 + sub * 64 + o) * HW + half * 2048) + threadIdx.x;
    float* dst = out + (size_t)(n * 256 + shuf_ch(64 * (sub + 1) + o)) * HW +
                 half * 2048 + threadIdx.x * 8;
    uint4 r = *src;
    float4 f0, f1;
    f0.x = fmaf(bf16lo(r.x), scale, shift);
    f0.y = fmaf(bf16hi(r.x), scale, shift);
    f0.z = fmaf(bf16lo(r.y), scale, shift);
    f0.w = fmaf(bf16hi(r.y), scale, shift);
    f1.x = fmaf(bf16lo(r.z), scale, shift);
    f1.y = fmaf(bf16hi(r.z), scale, shift);
    f1.z = fmaf(bf16lo(r.w), scale, shift);
    f1.w = fmaf(bf16hi(r.w), scale, shift);
    *(float4*)dst = f0;
    *(float4*)(dst + 4) = f1;
}

extern "C" void kernel_launch(void* const* d_in, const int* in_sizes, int n_in,
                              void* d_out, int out_size, void* d_ws, size_t ws_size,
                              hipStream_t stream) {
    const float* x        = (const float*)d_in[0];
    const float* sq_att_w = (const float*)d_in[1];
    const float* sq_att_b = (const float*)d_in[2];
    const float* sq_w     = (const float*)d_in[3];
    const float* sq_g     = (const float*)d_in[4];
    const float* sq_b     = (const float*)d_in[5];
    const float* ver_att_w= (const float*)d_in[6];
    const float* ver_att_b= (const float*)d_in[7];
    const float* ver_w    = (const float*)d_in[8];
    const float* ver_g    = (const float*)d_in[9];
    const float* ver_b    = (const float*)d_in[10];
    const float* hor_att_w= (const float*)d_in[11];
    const float* hor_att_b= (const float*)d_in[12];
    const float* hor_w    = (const float*)d_in[13];
    const float* hor_g    = (const float*)d_in[14];
    const float* hor_b    = (const float*)d_in[15];
    float* out = (float*)d_out;
    float* ws = (float*)d_ws;

    float* pooled = ws + WS_POOLED;
    float* ss     = ws + WS_SS;
    float* pst    = ws + WS_PST;
    unsigned* wbf_sq  = (unsigned*)(ws + WS_WBF_SQ);
    unsigned* wbf_ver = (unsigned*)(ws + WS_WBF_VER);
    unsigned* wbf_hor = (unsigned*)(ws + WS_WBF_HOR);
    unsigned char* xt = (unsigned char*)(ws + WS_XT);
    unsigned short* cvout = (unsigned short*)(ws + WS_CVOUT);

    prepass_kernel<<<3072, 256, 0, stream>>>(x, xt, pooled);
    aggbf_all_kernel<<<3840, 256, 0, stream>>>(pooled,
                                               sq_att_w, sq_att_b,
                                               ver_att_w, ver_att_b,
                                               hor_att_w, hor_att_b,
                                               sq_w, ver_w, hor_w,
                                               wbf_sq, wbf_ver, wbf_hor);
    conv_all_kernel<<<1792, 256, 0, stream>>>(x, xt, wbf_sq, wbf_ver, wbf_hor,
                                              cvout, pst, out);
    bnstats_all_kernel<<<192, 256, 0, stream>>>(pst, sq_g, sq_b, ver_g, ver_b,
                                                hor_g, hor_b, ss);
    bn_all_kernel<<<12288, 256, 0, stream>>>(cvout, out, ss);
}